// Round 5
// baseline (2193.459 us; speedup 1.0000x reference)
//
#include <hip/hip_runtime.h>
#include <hip/hip_bf16.h>

typedef short short8 __attribute__((ext_vector_type(8)));
typedef float f32x4 __attribute__((ext_vector_type(4)));

#define S_   64
#define NL_  5000
#define PD_  1024
#define LD_  768
#define DIM_ 512
#define OD_  512

#define BK     32
#define KSTEPS 16          // DIM_/BK
#define NT_M   79          // ceil(5000/64) n-tiles for main
#define HL_RT  157         // ceil(5000/32) row-tiles for hl

__device__ __forceinline__ ushort f2bf(float f) {
    union { float f; unsigned u; } v; v.f = f;
    unsigned r = v.u + 0x7fffu + ((v.u >> 16) & 1u);   // RNE
    return (ushort)(r >> 16);
}
__device__ __forceinline__ float bf2f(ushort h) {
    union { unsigned u; float f; } v; v.u = ((unsigned)h) << 16;
    return v.f;
}
// XOR swizzle for 64B-stride row tiles: conflict-free for write pattern
// (4 consecutive lanes = 1 row) and read pattern (16 lanes = 16 consecutive
// rows, fixed kslot). Bijective within each 1KB group.
__device__ __forceinline__ int swz(int row, int kslot) {
    return (row * 64 + kslot * 16) ^ (((row >> 1) & 7) << 4);
}
__device__ __forceinline__ void glds16(const void* g, void* l) {
    __builtin_amdgcn_global_load_lds(
        (const __attribute__((address_space(1))) void*)g,
        (__attribute__((address_space(3))) void*)l, 16, 0, 0);
}

// ==== pre-pass 1: {W2 panel prep | M_lT | P_e = P_f @ W_p.T} ================
__global__ __launch_bounds__(256) void k_pre1(
    const float* __restrict__ W2, const float* __restrict__ W_l,
    const float* __restrict__ W1, const float* __restrict__ P_f,
    const float* __restrict__ W_p,
    char* __restrict__ panel, ushort* __restrict__ MlT, float* __restrict__ P_e) {
    __shared__ float w1r[8][DIM_];
    int b = blockIdx.x, t = threadIdx.x;
    if (b < 128) {
        int c = b * 256 + t;                   // 32768 16B-chunks
        int o = c >> 6, rem = c & 63, kt = rem >> 2, kslot = rem & 3;
        const float* src = W2 + o * DIM_ + kt * BK + kslot * 8;
        float4 v0 = *(const float4*)src;
        float4 v1 = *(const float4*)(src + 4);
        union { ushort u[8]; short8 v; } pk;
        pk.u[0] = f2bf(v0.x); pk.u[1] = f2bf(v0.y); pk.u[2] = f2bf(v0.z); pk.u[3] = f2bf(v0.w);
        pk.u[4] = f2bf(v1.x); pk.u[5] = f2bf(v1.y); pk.u[6] = f2bf(v1.z); pk.u[7] = f2bf(v1.w);
        *(short8*)(panel + kt * 32768 + swz(o, kslot)) = pk.v;
    } else if (b < 320) {
        int bx = b - 128;
        int o0 = (bx / 3) * 8;
        int ld = (bx % 3) * 256 + t;
        for (int i = t; i < 8 * DIM_; i += 256)
            w1r[i >> 9][i & 511] = W1[(o0 + (i >> 9)) * (2 * DIM_) + DIM_ + (i & 511)];
        __syncthreads();
        float acc[8] = {};
        for (int dim = 0; dim < DIM_; dim++) {
            float wl = W_l[dim * LD_ + ld];
#pragma unroll
            for (int oi = 0; oi < 8; oi++) acc[oi] += w1r[oi][dim] * wl;
        }
#pragma unroll
        for (int oi = 0; oi < 8; oi++) MlT[(o0 + oi) * LD_ + ld] = f2bf(acc[oi]);
    } else {
        int o = b - 320;
        int s = t >> 2, kk = t & 3;
        const float* a = P_f + s * PD_ + kk * 256;
        const float* w = W_p + (size_t)o * PD_ + kk * 256;
        float acc = 0.f;
        for (int k = 0; k < 256; k += 4) {
            float4 av = *(const float4*)(a + k);
            float4 wv = *(const float4*)(w + k);
            acc += av.x * wv.x + av.y * wv.y + av.z * wv.z + av.w * wv.w;
        }
        acc += __shfl_xor(acc, 1, 64);
        acc += __shfl_xor(acc, 2, 64);
        if (kk == 0) P_e[s * DIM_ + o] = acc;
    }
}

// ==== pre-pass 2: {hpb = P_e @ W1p.T + b1 | hlB = bf16(emb[L]) @ MlT} =======
__global__ __launch_bounds__(256) void k_pre2(
    const float* __restrict__ P_e, const float* __restrict__ W1,
    const float* __restrict__ b1, const float* __restrict__ emb,
    const int* __restrict__ L, const ushort* __restrict__ MlT,
    float* __restrict__ hpb, ushort* __restrict__ hlB) {
    int b = blockIdx.x, t = threadIdx.x;
    if (b < 512) {
        int o = b;
        int s = t >> 2, kk = t & 3;
        const float* a = P_e + s * DIM_ + kk * 128;
        const float* w = W1 + (size_t)o * (2 * DIM_) + kk * 128;
        float acc = 0.f;
        for (int k = 0; k < 128; k += 4) {
            float4 av = *(const float4*)(a + k);
            float4 wv = *(const float4*)(w + k);
            acc += av.x * wv.x + av.y * wv.y + av.z * wv.z + av.w * wv.w;
        }
        acc += __shfl_xor(acc, 1, 64);
        acc += __shfl_xor(acc, 2, 64);
        if (kk == 0) hpb[s * DIM_ + o] = acc + b1[o];
    } else {
        int hb = b - 512;                     // 0..313
        int rblk = hb % HL_RT, oh = hb / HL_RT;
        int r0 = rblk * 32;
        int w = t >> 6, l = t & 63, lg = l >> 4, ll = l & 15;
        const float* arow[2];
#pragma unroll
        for (int mt = 0; mt < 2; mt++) {
            int r = r0 + mt * 16 + ll;
            if (r >= NL_) r = NL_ - 1;
            arow[mt] = emb + (size_t)L[r] * LD_ + lg * 8;
        }
        f32x4 acc[2][4] = {};
        for (int k = 0; k < LD_; k += 32) {
            short8 a[2], bf[4];
#pragma unroll
            for (int mt = 0; mt < 2; mt++) {
                float4 v0 = *(const float4*)(arow[mt] + k);
                float4 v1 = *(const float4*)(arow[mt] + k + 4);
                union { ushort u[8]; short8 v; } pk;
                pk.u[0] = f2bf(v0.x); pk.u[1] = f2bf(v0.y);
                pk.u[2] = f2bf(v0.z); pk.u[3] = f2bf(v0.w);
                pk.u[4] = f2bf(v1.x); pk.u[5] = f2bf(v1.y);
                pk.u[6] = f2bf(v1.z); pk.u[7] = f2bf(v1.w);
                a[mt] = pk.v;
            }
#pragma unroll
            for (int ot = 0; ot < 4; ot++) {
                int o = oh * 256 + w * 64 + ot * 16 + ll;
                bf[ot] = *(const short8*)(MlT + o * LD_ + k + lg * 8);
            }
#pragma unroll
            for (int mt = 0; mt < 2; mt++)
#pragma unroll
                for (int ot = 0; ot < 4; ot++)
                    acc[mt][ot] = __builtin_amdgcn_mfma_f32_16x16x32_bf16(a[mt], bf[ot], acc[mt][ot], 0, 0, 0);
        }
#pragma unroll
        for (int mt = 0; mt < 2; mt++)
#pragma unroll
            for (int ot = 0; ot < 4; ot++)
#pragma unroll
                for (int reg = 0; reg < 4; reg++) {
                    int r = r0 + mt * 16 + lg * 4 + reg;
                    if (r < NL_)
                        hlB[(size_t)r * DIM_ + oh * 256 + w * 64 + ot * 16 + ll] = f2bf(acc[mt][ot][reg]);
                }
    }
}

// ==== main: BM=256 (4s x 64n) x BN=512, BK=32, counted-vmcnt pipeline =======
// 16 waves (4M x 4N), wave tile 64x128, acc[4][8].
// LDS 128KB: A 2x16KB dbuf + B 3x32KB triple-buf -> 1 block/CU.
// Pipeline: stage(kt+2) in flight across barriers; per-iter wait is
// vmcnt(2) (prev tile's own 2 glds) + lgkmcnt(0) (own packA write).
__global__ __launch_bounds__(1024, 4) void k_main2(
    const ushort* __restrict__ hlB, const float* __restrict__ hpb,
    const char* __restrict__ panel, const float* __restrict__ b2,
    const float* __restrict__ W3, const float* __restrict__ b3,
    float* __restrict__ out) {
    __shared__ f32x4 ldsv[8192];            // 131072 B
    char* lds = (char*)ldsv;
    const int t = threadIdx.x;
    const int n0 = blockIdx.x * 64, s0 = blockIdx.y * 4;
    const int w = t >> 6, lane = t & 63, lg = lane >> 4, ll = lane & 15;
    const int wr = w >> 2, wc = w & 3;      // 4M x 4N wave grid

    // A-staging: thread t owns one 16B chunk (row = t>>2, kslot = t&3)
    const int arow = t >> 2, akslot = t & 3;
    int an = n0 + (arow & 63); if (an >= NL_) an = NL_ - 1;
    const ushort* hlsrc = hlB + (size_t)an * DIM_ + akslot * 8;
    const float*  hpsrc = hpb + (s0 + (arow >> 6)) * DIM_ + akslot * 8;
    const int awz = swz(arow, akslot);

    int aoffS[4], boffS[8];
#pragma unroll
    for (int mt = 0; mt < 4; mt++) aoffS[mt] = swz(wr * 64 + mt * 16 + ll, lg);
#pragma unroll
    for (int ot = 0; ot < 8; ot++) boffS[ot] = swz(wc * 128 + ot * 16 + ll, lg);

    f32x4 acc[4][8] = {};

    // B-stage: per wave 2 x 1KB chunks; LDS dest wave-uniform, global per-lane.
    auto stageB = [&](int kt, int buf) {
        const char* base = panel + kt * 32768 + w * 2048 + (lane << 4);
        char* ldsB = lds + 32768 + buf * 32768 + w * 2048;
        glds16(base, ldsB);
        glds16(base + 1024, ldsB + 1024);
    };
    auto packA = [&](int buf, short8 hv, float4 p0, float4 p1) {
        float hp8[8] = { p0.x, p0.y, p0.z, p0.w, p1.x, p1.y, p1.z, p1.w };
        float x[8];
#pragma unroll
        for (int e = 0; e < 8; e++) {
            float s = bf2f((ushort)hv[e]) + hp8[e];
            x[e] = s > 0.f ? s : 0.f;
        }
        union { __hip_bfloat162 h2[4]; short8 v; } pk;
#pragma unroll
        for (int e = 0; e < 4; e++)
            pk.h2[e] = __float22bfloat162_rn(make_float2(x[2 * e], x[2 * e + 1]));
        *(short8*)(lds + buf * 16384 + awz) = pk.v;
    };

    // ---- prologue: regs(0) first, then stage(0)+stage(1); packA(0) ----
    {
        short8 hv = *(const short8*)(hlsrc);
        float4 p0 = *(const float4*)(hpsrc);
        float4 p1 = *(const float4*)(hpsrc + 4);
        __builtin_amdgcn_sched_barrier(0);
        stageB(0, 0);
        stageB(1, 1);
        __builtin_amdgcn_sched_barrier(0);
        packA(0, hv, p0, p1);                 // compiler waits vmcnt(4)
        asm volatile("s_waitcnt vmcnt(2) lgkmcnt(0)" ::: "memory");
        __builtin_amdgcn_s_barrier();
    }

#pragma unroll
    for (int kt = 0; kt < KSTEPS; kt++) {
        short8 hv; float4 p0, p1;
        if (kt + 1 < KSTEPS) {                // reg loads FIRST (so packA's
            hv = *(const short8*)(hlsrc + (kt + 1) * BK);   // auto-wait is
            p0 = *(const float4*)(hpsrc + (kt + 1) * BK);   // counted, not 0)
            p1 = *(const float4*)(hpsrc + (kt + 1) * BK + 4);
        }
        __builtin_amdgcn_sched_barrier(0);
        if (kt + 2 < KSTEPS) stageB(kt + 2, (kt + 2) % 3);  // 2-deep prefetch
        __builtin_amdgcn_sched_barrier(0);
        const char* A = lds + (kt & 1) * 16384;
        const char* B = lds + 32768 + (kt % 3) * 32768;
        short8 a[4], b[8];
#pragma unroll
        for (int mt = 0; mt < 4; mt++) a[mt] = *(const short8*)(A + aoffS[mt]);
#pragma unroll
        for (int ot = 0; ot < 8; ot++) b[ot] = *(const short8*)(B + boffS[ot]);
        __builtin_amdgcn_s_setprio(1);
#pragma unroll
        for (int mt = 0; mt < 4; mt++)
#pragma unroll
            for (int ot = 0; ot < 8; ot++)
                acc[mt][ot] = __builtin_amdgcn_mfma_f32_16x16x32_bf16(a[mt], b[ot], acc[mt][ot], 0, 0, 0);
        __builtin_amdgcn_s_setprio(0);
        if (kt + 1 < KSTEPS) packA((kt + 1) & 1, hv, p0, p1);
        // own prev-tile glds done (next-tile's 2 may stay in flight) +
        // own packA ds_write drained; barrier makes it block-wide.
        asm volatile("s_waitcnt vmcnt(2) lgkmcnt(0)" ::: "memory");
        __builtin_amdgcn_s_barrier();
    }

    // ---- epilogue: relu(acc+b2)*W3, reduce over o; direct out write ----
    float* logit = (float*)lds;                           // reuse A buf 0
    if (t < 256) logit[t] = 0.f;
    __syncthreads();
#pragma unroll
    for (int mt = 0; mt < 4; mt++) {
        float p4[4] = { 0.f, 0.f, 0.f, 0.f };
#pragma unroll
        for (int ot = 0; ot < 8; ot++) {
            int o = wc * 128 + ot * 16 + ll;
            float bb = b2[o], w3 = W3[o];
#pragma unroll
            for (int reg = 0; reg < 4; reg++) {
                float v = acc[mt][ot][reg] + bb;
                v = v > 0.f ? v : 0.f;
                p4[reg] += v * w3;
            }
        }
#pragma unroll
        for (int m = 1; m < 16; m <<= 1)
#pragma unroll
            for (int reg = 0; reg < 4; reg++) p4[reg] += __shfl_xor(p4[reg], m, 64);
        if (ll == 0)
#pragma unroll
            for (int reg = 0; reg < 4; reg++)
                atomicAdd(&logit[wr * 64 + mt * 16 + lg * 4 + reg], p4[reg]);
    }
    __syncthreads();
    if (t < 256) {
        int n = n0 + (t & 63);
        int s = s0 + (t >> 6);
        if (n < NL_) out[(size_t)s * NL_ + n] = logit[t] + b3[0];
    }
}

extern "C" void kernel_launch(void* const* d_in, const int* in_sizes, int n_in,
                              void* d_out, int out_size, void* d_ws, size_t ws_size,
                              hipStream_t stream) {
    const float* P_f = (const float*)d_in[0];
    const float* emb = (const float*)d_in[1];
    const float* W_p = (const float*)d_in[2];
    const float* W_l = (const float*)d_in[3];
    const float* W1  = (const float*)d_in[4];
    const float* b1  = (const float*)d_in[5];
    const float* W2  = (const float*)d_in[6];
    const float* b2  = (const float*)d_in[7];
    const float* W3  = (const float*)d_in[8];
    const float* b3  = (const float*)d_in[9];
    const int*   L   = (const int*)d_in[10];
    float* out = (float*)d_out;

    char* ws = (char*)d_ws;
    size_t off = 0;
    auto alloc = [&](size_t bytes) {
        void* p = ws + off;
        off = (off + bytes + 255) & ~(size_t)255;
        return p;
    };
    char*   panel = (char*)alloc((size_t)KSTEPS * 32768);            // 512 KB
    ushort* MlT   = (ushort*)alloc((size_t)OD_ * LD_ * 2);           // 768 KB
    float*  P_e   = (float*)alloc((size_t)S_ * DIM_ * 4);
    float*  hpb   = (float*)alloc((size_t)S_ * DIM_ * 4);
    ushort* hlB   = (ushort*)alloc((size_t)NL_ * DIM_ * 2);          // 5.12 MB

    k_pre1<<<832, 256, 0, stream>>>(W2, W_l, W1, P_f, W_p, panel, MlT, P_e);
    k_pre2<<<826, 256, 0, stream>>>(P_e, W1, b1, emb, L, MlT, hpb, hlB);
    k_main2<<<dim3(NT_M, 16), 1024, 0, stream>>>(hlB, hpb, panel, b2, W3, b3, out);
}

// Round 6
// 308.416 us; speedup vs baseline: 7.1120x; 7.1120x over previous
//
#include <hip/hip_runtime.h>
#include <hip/hip_bf16.h>

typedef short short8 __attribute__((ext_vector_type(8)));
typedef float f32x4 __attribute__((ext_vector_type(4)));

#define S_   64
#define NL_  5000
#define PD_  1024
#define LD_  768
#define DIM_ 512
#define OD_  512

#define BK     32
#define KSTEPS 16          // DIM_/BK
#define NT_M   79          // ceil(5000/64) n-tiles for main
#define HL_RT  157         // ceil(5000/32) row-tiles for hl

__device__ __forceinline__ ushort f2bf(float f) {
    union { float f; unsigned u; } v; v.f = f;
    unsigned r = v.u + 0x7fffu + ((v.u >> 16) & 1u);   // RNE
    return (ushort)(r >> 16);
}
__device__ __forceinline__ float bf2f(ushort h) {
    union { unsigned u; float f; } v; v.u = ((unsigned)h) << 16;
    return v.f;
}
// XOR swizzle for 64B-stride row tiles: conflict-free for write pattern
// (4 consecutive lanes = 1 row) and read pattern (16 lanes = 16 consecutive
// rows, fixed kslot). Bijective within each 1KB group.
__device__ __forceinline__ int swz(int row, int kslot) {
    return (row * 64 + kslot * 16) ^ (((row >> 1) & 7) << 4);
}
__device__ __forceinline__ void glds16(const void* g, void* l) {
    __builtin_amdgcn_global_load_lds(
        (const __attribute__((address_space(1))) void*)g,
        (__attribute__((address_space(3))) void*)l, 16, 0, 0);
}

// ==== pre-pass 1: {W2 panel prep | M_lT | P_e = P_f @ W_p.T} ================
__global__ __launch_bounds__(256) void k_pre1(
    const float* __restrict__ W2, const float* __restrict__ W_l,
    const float* __restrict__ W1, const float* __restrict__ P_f,
    const float* __restrict__ W_p,
    char* __restrict__ panel, ushort* __restrict__ MlT, float* __restrict__ P_e) {
    __shared__ float w1r[8][DIM_];
    int b = blockIdx.x, t = threadIdx.x;
    if (b < 128) {
        int c = b * 256 + t;                   // 32768 16B-chunks
        int o = c >> 6, rem = c & 63, kt = rem >> 2, kslot = rem & 3;
        const float* src = W2 + o * DIM_ + kt * BK + kslot * 8;
        float4 v0 = *(const float4*)src;
        float4 v1 = *(const float4*)(src + 4);
        union { ushort u[8]; short8 v; } pk;
        pk.u[0] = f2bf(v0.x); pk.u[1] = f2bf(v0.y); pk.u[2] = f2bf(v0.z); pk.u[3] = f2bf(v0.w);
        pk.u[4] = f2bf(v1.x); pk.u[5] = f2bf(v1.y); pk.u[6] = f2bf(v1.z); pk.u[7] = f2bf(v1.w);
        *(short8*)(panel + kt * 32768 + swz(o, kslot)) = pk.v;
    } else if (b < 320) {
        int bx = b - 128;
        int o0 = (bx / 3) * 8;
        int ld = (bx % 3) * 256 + t;
        for (int i = t; i < 8 * DIM_; i += 256)
            w1r[i >> 9][i & 511] = W1[(o0 + (i >> 9)) * (2 * DIM_) + DIM_ + (i & 511)];
        __syncthreads();
        float acc[8] = {};
        for (int dim = 0; dim < DIM_; dim++) {
            float wl = W_l[dim * LD_ + ld];
#pragma unroll
            for (int oi = 0; oi < 8; oi++) acc[oi] += w1r[oi][dim] * wl;
        }
#pragma unroll
        for (int oi = 0; oi < 8; oi++) MlT[(o0 + oi) * LD_ + ld] = f2bf(acc[oi]);
    } else {
        int o = b - 320;
        int s = t >> 2, kk = t & 3;
        const float* a = P_f + s * PD_ + kk * 256;
        const float* w = W_p + (size_t)o * PD_ + kk * 256;
        float acc = 0.f;
        for (int k = 0; k < 256; k += 4) {
            float4 av = *(const float4*)(a + k);
            float4 wv = *(const float4*)(w + k);
            acc += av.x * wv.x + av.y * wv.y + av.z * wv.z + av.w * wv.w;
        }
        acc += __shfl_xor(acc, 1, 64);
        acc += __shfl_xor(acc, 2, 64);
        if (kk == 0) P_e[s * DIM_ + o] = acc;
    }
}

// ==== pre-pass 2: {hpb = P_e @ W1p.T + b1 | hlB = bf16(emb[L]) @ MlT} =======
__global__ __launch_bounds__(256) void k_pre2(
    const float* __restrict__ P_e, const float* __restrict__ W1,
    const float* __restrict__ b1, const float* __restrict__ emb,
    const int* __restrict__ L, const ushort* __restrict__ MlT,
    float* __restrict__ hpb, ushort* __restrict__ hlB) {
    int b = blockIdx.x, t = threadIdx.x;
    if (b < 512) {
        int o = b;
        int s = t >> 2, kk = t & 3;
        const float* a = P_e + s * DIM_ + kk * 128;
        const float* w = W1 + (size_t)o * (2 * DIM_) + kk * 128;
        float acc = 0.f;
        for (int k = 0; k < 128; k += 4) {
            float4 av = *(const float4*)(a + k);
            float4 wv = *(const float4*)(w + k);
            acc += av.x * wv.x + av.y * wv.y + av.z * wv.z + av.w * wv.w;
        }
        acc += __shfl_xor(acc, 1, 64);
        acc += __shfl_xor(acc, 2, 64);
        if (kk == 0) hpb[s * DIM_ + o] = acc + b1[o];
    } else {
        int hb = b - 512;                     // 0..313
        int rblk = hb % HL_RT, oh = hb / HL_RT;
        int r0 = rblk * 32;
        int w = t >> 6, l = t & 63, lg = l >> 4, ll = l & 15;
        const float* arow[2];
#pragma unroll
        for (int mt = 0; mt < 2; mt++) {
            int r = r0 + mt * 16 + ll;
            if (r >= NL_) r = NL_ - 1;
            arow[mt] = emb + (size_t)L[r] * LD_ + lg * 8;
        }
        f32x4 acc[2][4] = {};
        for (int k = 0; k < LD_; k += 32) {
            short8 a[2], bf[4];
#pragma unroll
            for (int mt = 0; mt < 2; mt++) {
                float4 v0 = *(const float4*)(arow[mt] + k);
                float4 v1 = *(const float4*)(arow[mt] + k + 4);
                union { ushort u[8]; short8 v; } pk;
                pk.u[0] = f2bf(v0.x); pk.u[1] = f2bf(v0.y);
                pk.u[2] = f2bf(v0.z); pk.u[3] = f2bf(v0.w);
                pk.u[4] = f2bf(v1.x); pk.u[5] = f2bf(v1.y);
                pk.u[6] = f2bf(v1.z); pk.u[7] = f2bf(v1.w);
                a[mt] = pk.v;
            }
#pragma unroll
            for (int ot = 0; ot < 4; ot++) {
                int o = oh * 256 + w * 64 + ot * 16 + ll;
                bf[ot] = *(const short8*)(MlT + o * LD_ + k + lg * 8);
            }
#pragma unroll
            for (int mt = 0; mt < 2; mt++)
#pragma unroll
                for (int ot = 0; ot < 4; ot++)
                    acc[mt][ot] = __builtin_amdgcn_mfma_f32_16x16x32_bf16(a[mt], bf[ot], acc[mt][ot], 0, 0, 0);
        }
#pragma unroll
        for (int mt = 0; mt < 2; mt++)
#pragma unroll
            for (int ot = 0; ot < 4; ot++)
#pragma unroll
                for (int reg = 0; reg < 4; reg++) {
                    int r = r0 + mt * 16 + lg * 4 + reg;
                    if (r < NL_)
                        hlB[(size_t)r * DIM_ + oh * 256 + w * 64 + ot * 16 + ll] = f2bf(acc[mt][ot][reg]);
                }
    }
}

// ==== main: BM=128 (2s x 64n) x BN=512, BK=32, counted-vmcnt pipeline =======
// 8 waves (2M x 4N), wave tile 64x128, acc[4][8]. 512 threads (round-4 shape:
// VGPR=100+AGPR acc, no spill; 1024-thr variant spilled catastrophically).
// LDS 112KB: A 2x8KB dbuf + B 3x32KB triple-buf -> 1 block/CU.
// Per-iter wait: vmcnt(4) (prev tile's own 4 glds done, next tile's 4 stay
// in flight across the barrier) + lgkmcnt(0) (own packA ds_write drained).
__global__ __launch_bounds__(512, 2) void k_main2(
    const ushort* __restrict__ hlB, const float* __restrict__ hpb,
    const char* __restrict__ panel, const float* __restrict__ b2,
    const float* __restrict__ W3, const float* __restrict__ b3,
    float* __restrict__ out) {
    __shared__ f32x4 ldsv[7168];            // 114688 B
    char* lds = (char*)ldsv;
    const int t = threadIdx.x;
    const int n0 = blockIdx.x * 64, s0 = blockIdx.y * 2;
    const int w = t >> 6, lane = t & 63, lg = lane >> 4, ll = lane & 15;
    const int wr = w >> 2, wc = w & 3;      // 2M x 4N wave grid

    // A-staging: thread t owns one 16B chunk (row = t>>2, kslot = t&3)
    const int arow = t >> 2, akslot = t & 3;
    int an = n0 + (arow & 63); if (an >= NL_) an = NL_ - 1;
    const ushort* hlsrc = hlB + (size_t)an * DIM_ + akslot * 8;
    const float*  hpsrc = hpb + (s0 + (arow >> 6)) * DIM_ + akslot * 8;
    const int awz = swz(arow, akslot);

    int aoffS[4], boffS[8];
#pragma unroll
    for (int mt = 0; mt < 4; mt++) aoffS[mt] = swz(wr * 64 + mt * 16 + ll, lg);
#pragma unroll
    for (int ot = 0; ot < 8; ot++) boffS[ot] = swz(wc * 128 + ot * 16 + ll, lg);

    f32x4 acc[4][8] = {};

    // B-stage: per wave 4 x 1KB chunks (4 glds/thread); LDS dest wave-uniform.
    auto stageB = [&](int kt, int buf) {
        const char* base = panel + kt * 32768 + w * 4096 + (lane << 4);
        char* ldsB = lds + 16384 + buf * 32768 + w * 4096;
#pragma unroll
        for (int r = 0; r < 4; r++) glds16(base + r * 1024, ldsB + r * 1024);
    };
    auto packA = [&](int buf, short8 hv, float4 p0, float4 p1) {
        float hp8[8] = { p0.x, p0.y, p0.z, p0.w, p1.x, p1.y, p1.z, p1.w };
        float x[8];
#pragma unroll
        for (int e = 0; e < 8; e++) {
            float s = bf2f((ushort)hv[e]) + hp8[e];
            x[e] = s > 0.f ? s : 0.f;
        }
        union { __hip_bfloat162 h2[4]; short8 v; } pk;
#pragma unroll
        for (int e = 0; e < 4; e++)
            pk.h2[e] = __float22bfloat162_rn(make_float2(x[2 * e], x[2 * e + 1]));
        *(short8*)(lds + buf * 8192 + awz) = pk.v;
    };

    // ---- prologue: regs(0), stage(0), stage(1); packA(0); counted wait ----
    {
        short8 hv = *(const short8*)(hlsrc);
        float4 p0 = *(const float4*)(hpsrc);
        float4 p1 = *(const float4*)(hpsrc + 4);
        __builtin_amdgcn_sched_barrier(0);
        stageB(0, 0);
        stageB(1, 1);
        __builtin_amdgcn_sched_barrier(0);
        packA(0, hv, p0, p1);                 // auto-wait leaves stages in flight
        asm volatile("s_waitcnt vmcnt(4) lgkmcnt(0)" ::: "memory");
        __builtin_amdgcn_s_barrier();
    }

    for (int kt = 0; kt < KSTEPS; kt++) {
        short8 hv; float4 p0, p1;
        if (kt + 1 < KSTEPS) {                // reg loads FIRST so packA's
            hv = *(const short8*)(hlsrc + (kt + 1) * BK);   // auto-wait is
            p0 = *(const float4*)(hpsrc + (kt + 1) * BK);   // counted, not 0
            p1 = *(const float4*)(hpsrc + (kt + 1) * BK + 4);
        }
        __builtin_amdgcn_sched_barrier(0);
        if (kt + 2 < KSTEPS) stageB(kt + 2, (kt + 2) % 3);  // 2-deep prefetch
        __builtin_amdgcn_sched_barrier(0);
        const char* A = lds + (kt & 1) * 8192;
        const char* B = lds + 16384 + (kt % 3) * 32768;
        short8 a[4], b[8];
#pragma unroll
        for (int mt = 0; mt < 4; mt++) a[mt] = *(const short8*)(A + aoffS[mt]);
#pragma unroll
        for (int ot = 0; ot < 8; ot++) b[ot] = *(const short8*)(B + boffS[ot]);
        __builtin_amdgcn_s_setprio(1);
#pragma unroll
        for (int mt = 0; mt < 4; mt++)
#pragma unroll
            for (int ot = 0; ot < 8; ot++)
                acc[mt][ot] = __builtin_amdgcn_mfma_f32_16x16x32_bf16(a[mt], b[ot], acc[mt][ot], 0, 0, 0);
        __builtin_amdgcn_s_setprio(0);
        if (kt + 1 < KSTEPS) packA((kt + 1) & 1, hv, p0, p1);
        // own prev-tile glds done (next tile's 4 stay in flight) + own
        // packA ds_write drained; barrier makes it block-wide.
        asm volatile("s_waitcnt vmcnt(4) lgkmcnt(0)" ::: "memory");
        __builtin_amdgcn_s_barrier();
    }

    // ---- epilogue: relu(acc+b2)*W3, reduce over o; direct out write ----
    float* logit = (float*)lds;                           // reuse A buf 0
    if (t < 128) logit[t] = 0.f;
    __syncthreads();
#pragma unroll
    for (int mt = 0; mt < 4; mt++) {
        float p4[4] = { 0.f, 0.f, 0.f, 0.f };
#pragma unroll
        for (int ot = 0; ot < 8; ot++) {
            int o = wc * 128 + ot * 16 + ll;
            float bb = b2[o], w3 = W3[o];
#pragma unroll
            for (int reg = 0; reg < 4; reg++) {
                float v = acc[mt][ot][reg] + bb;
                v = v > 0.f ? v : 0.f;
                p4[reg] += v * w3;
            }
        }
#pragma unroll
        for (int m = 1; m < 16; m <<= 1)
#pragma unroll
            for (int reg = 0; reg < 4; reg++) p4[reg] += __shfl_xor(p4[reg], m, 64);
        if (ll == 0)
#pragma unroll
            for (int reg = 0; reg < 4; reg++)
                atomicAdd(&logit[wr * 64 + mt * 16 + lg * 4 + reg], p4[reg]);
    }
    __syncthreads();
    if (t < 128) {
        int n = n0 + (t & 63);
        int s = s0 + (t >> 6);
        if (n < NL_) out[(size_t)s * NL_ + n] = logit[t] + b3[0];
    }
}

extern "C" void kernel_launch(void* const* d_in, const int* in_sizes, int n_in,
                              void* d_out, int out_size, void* d_ws, size_t ws_size,
                              hipStream_t stream) {
    const float* P_f = (const float*)d_in[0];
    const float* emb = (const float*)d_in[1];
    const float* W_p = (const float*)d_in[2];
    const float* W_l = (const float*)d_in[3];
    const float* W1  = (const float*)d_in[4];
    const float* b1  = (const float*)d_in[5];
    const float* W2  = (const float*)d_in[6];
    const float* b2  = (const float*)d_in[7];
    const float* W3  = (const float*)d_in[8];
    const float* b3  = (const float*)d_in[9];
    const int*   L   = (const int*)d_in[10];
    float* out = (float*)d_out;

    char* ws = (char*)d_ws;
    size_t off = 0;
    auto alloc = [&](size_t bytes) {
        void* p = ws + off;
        off = (off + bytes + 255) & ~(size_t)255;
        return p;
    };
    char*   panel = (char*)alloc((size_t)KSTEPS * 32768);            // 512 KB
    ushort* MlT   = (ushort*)alloc((size_t)OD_ * LD_ * 2);           // 768 KB
    float*  P_e   = (float*)alloc((size_t)S_ * DIM_ * 4);
    float*  hpb   = (float*)alloc((size_t)S_ * DIM_ * 4);
    ushort* hlB   = (ushort*)alloc((size_t)NL_ * DIM_ * 2);          // 5.12 MB

    k_pre1<<<832, 256, 0, stream>>>(W2, W_l, W1, P_f, W_p, panel, MlT, P_e);
    k_pre2<<<826, 256, 0, stream>>>(P_e, W1, b1, emb, L, MlT, hpb, hlB);
    k_main2<<<dim3(NT_M, 32), 512, 0, stream>>>(hlB, hpb, panel, b2, W3, b3, out);
}